// Round 1
// baseline (123.754 us; speedup 1.0000x reference)
//
#include <hip/hip_runtime.h>

typedef int   v4i __attribute__((ext_vector_type(4)));
typedef float v4f __attribute__((ext_vector_type(4)));

#define NB 32
#define CI 128
#define HW 56
#define KOC 256
#define HP 58
#define MTOT (NB*HW*HW)          // 100352
#define XP_ELEMS (NB*HP*HP*CI)   // 13778944
#define WB_ELEMS (9*KOC*CI)      // 294912
#define XP_OFF_BYTES ((size_t)1<<20)

__device__ __forceinline__ unsigned short f2bf(float f) {
    unsigned int u = __builtin_bit_cast(unsigned int, f);
    u += 0x7fffu + ((u >> 16) & 1u);   // round-to-nearest-even
    return (unsigned short)(u >> 16);
}

// ---- transform: weight (256,128,3,3) f32 -> Wb[rs][ko][c] bf16 (c contiguous)
__global__ void wt_bf16(const float* __restrict__ w, unsigned short* __restrict__ wb) {
    int t = blockIdx.x * 256 + threadIdx.x;      // t = ko*128 + c
    if (t >= KOC * CI) return;
    const float* src = w + (size_t)t * 9;
    int ko = t >> 7, c = t & 127;
    #pragma unroll
    for (int rs = 0; rs < 9; ++rs)
        wb[(size_t)(rs * KOC + ko) * CI + c] = f2bf(src[rs]);
}

// ---- transform: x NCHW f32 -> padded NHWC bf16 Xp[n][58][58][128] (interior only)
__global__ void pad_nhwc_bf16(const float* __restrict__ x, unsigned short* __restrict__ xp) {
    __shared__ unsigned short tile[HW][136];     // [w][c], row 272B (16B aligned)
    int b = blockIdx.x;                          // n*56 + h
    int n = b / HW, h = b % HW;
    int tid = threadIdx.x;
    const float* xr = x + (size_t)n * CI * HW * HW + (size_t)h * HW;
    for (int idx = tid; idx < CI * HW; idx += 256) {
        int c = idx / HW, w = idx % HW;          // lanes contiguous in w -> coalesced read
        tile[w][c] = f2bf(xr[(size_t)c * (HW * HW) + w]);
    }
    __syncthreads();
    unsigned short* xpr = xp + ((size_t)(n * HP + (h + 1)) * HP + 1) * CI;
    for (int idx = tid; idx < (HW * CI) / 8; idx += 256) {   // 896 x 16B stores
        int w = idx >> 4, c8 = (idx & 15) * 8;
        *reinterpret_cast<uint4*>(xpr + (size_t)w * CI + c8) =
            *reinterpret_cast<const uint4*>(&tile[w][c8]);
    }
}

// ---- main: implicit-GEMM conv, D[ko][m] += W[ko][c] * X[c][m] over 9 (r,s) shifts
__global__ __launch_bounds__(256) void conv_mfma(
    const unsigned short* __restrict__ xp,
    const unsigned short* __restrict__ wb,
    const float* __restrict__ bias,
    float* __restrict__ out)
{
    __shared__ unsigned short sW[128][40];   // [ko][c], +8 pad -> 80B rows
    __shared__ unsigned short sX[128][40];   // [m][c]

    const int tid  = threadIdx.x;
    const int lane = tid & 63;
    const int wid  = tid >> 6;
    const int wko  = wid >> 1, wm = wid & 1;     // 2x2 wave grid of 64x64
    const int m0   = blockIdx.x * 128;
    const int ko0  = blockIdx.y * 128;

    const int r0 = tid >> 2;                 // staging row 0..63 (and +64)
    const int cp = (tid & 3) * 8;            // 16B chunk within 32-c row

    // X row bases (output-pixel -> padded NHWC offset), computed once
    int mA = m0 + r0,      mB = m0 + 64 + r0;
    int nA = mA / 3136, tA = mA % 3136, ohA = tA / 56, owA = tA % 56;
    int nB = mB / 3136, tB = mB % 3136, ohB = tB / 56, owB = tB % 56;
    size_t xbaseA = ((size_t)(nA * HP + ohA) * HP + owA) * CI;
    size_t xbaseB = ((size_t)(nB * HP + ohB) * HP + owB) * CI;
    size_t wbaseA = (size_t)(ko0 + r0) * CI + cp;
    size_t wbaseB = (size_t)(ko0 + 64 + r0) * CI + cp;

    v4f acc[4][4];
    const v4f vzero = {0.f, 0.f, 0.f, 0.f};
    #pragma unroll
    for (int a = 0; a < 4; ++a)
        #pragma unroll
        for (int b = 0; b < 4; ++b) acc[a][b] = vzero;

    auto ldg = [&](int it, v4i& w0, v4i& w1, v4i& x0, v4i& x1) {
        int rs = it >> 2;
        int cb = (it & 3) * 32;
        int r = rs / 3, s = rs % 3;
        size_t shift = (size_t)(r * HP + s) * CI + cb + cp;
        const unsigned short* wrow = wb + (size_t)rs * KOC * CI + cb;
        w0 = *reinterpret_cast<const v4i*>(wrow + wbaseA);
        w1 = *reinterpret_cast<const v4i*>(wrow + wbaseB);
        x0 = *reinterpret_cast<const v4i*>(xp + xbaseA + shift);
        x1 = *reinterpret_cast<const v4i*>(xp + xbaseB + shift);
    };

    v4i wv0, wv1, xv0, xv1;
    ldg(0, wv0, wv1, xv0, xv1);

    const int aRow = wko * 64 + (lane & 15);
    const int bRow = wm * 64 + (lane & 15);
    const int kOff = (lane >> 4) * 8;

    for (int it = 0; it < 36; ++it) {
        *reinterpret_cast<v4i*>(&sW[r0][cp])      = wv0;
        *reinterpret_cast<v4i*>(&sW[64 + r0][cp]) = wv1;
        *reinterpret_cast<v4i*>(&sX[r0][cp])      = xv0;
        *reinterpret_cast<v4i*>(&sX[64 + r0][cp]) = xv1;
        __syncthreads();

        int nx = (it + 1 < 36) ? it + 1 : 35;    // clamped redundant prefetch on last iter
        v4i wn0, wn1, xn0, xn1;
        ldg(nx, wn0, wn1, xn0, xn1);             // in-flight under MFMA phase

        v4i af[4], bf[4];
        #pragma unroll
        for (int a = 0; a < 4; ++a)
            af[a] = *reinterpret_cast<const v4i*>(&sW[aRow + a * 16][kOff]);
        #pragma unroll
        for (int b = 0; b < 4; ++b)
            bf[b] = *reinterpret_cast<const v4i*>(&sX[bRow + b * 16][kOff]);

        #pragma unroll
        for (int a = 0; a < 4; ++a)
            #pragma unroll
            for (int b = 0; b < 4; ++b)
                asm volatile("v_mfma_f32_16x16x32_bf16 %0, %1, %2, %0"
                             : "+v"(acc[a][b]) : "v"(af[a]), "v"(bf[b]));

        __syncthreads();
        wv0 = wn0; wv1 = wn1; xv0 = xn0; xv1 = xn1;
    }

    // MFMA->VALU hazard fence, ordered after all MFMAs and before any acc use
    asm volatile("s_nop 7\n\ts_nop 7\n\ts_nop 7"
        : "+v"(acc[0][0]), "+v"(acc[0][1]), "+v"(acc[0][2]), "+v"(acc[0][3]),
          "+v"(acc[1][0]), "+v"(acc[1][1]), "+v"(acc[1][2]), "+v"(acc[1][3]),
          "+v"(acc[2][0]), "+v"(acc[2][1]), "+v"(acc[2][2]), "+v"(acc[2][3]),
          "+v"(acc[3][0]), "+v"(acc[3][1]), "+v"(acc[3][2]), "+v"(acc[3][3]));

    // epilogue: D row=(lane>>4)*4+reg -> ko ; col=lane&15 -> m (coalesced stores)
    const int koBase = ko0 + wko * 64 + (lane >> 4) * 4;
    float bv[4][4];
    #pragma unroll
    for (int a = 0; a < 4; ++a)
        #pragma unroll
        for (int r = 0; r < 4; ++r)
            bv[a][r] = bias[koBase + a * 16 + r];

    #pragma unroll
    for (int b = 0; b < 4; ++b) {
        int mcol = m0 + wm * 64 + b * 16 + (lane & 15);
        int n = mcol / 3136, t4 = mcol % 3136, oh = t4 / 56, ow = t4 % 56;
        size_t obase = (size_t)n * (KOC * 3136) + (size_t)oh * 56 + ow;
        #pragma unroll
        for (int a = 0; a < 4; ++a) {
            int kk = koBase + a * 16;
            #pragma unroll
            for (int r = 0; r < 4; ++r)
                out[obase + (size_t)(kk + r) * 3136] = acc[a][b][r] + bv[a][r];
        }
    }
}

// ---- insurance path if workspace is too small: naive direct conv (correct, slow)
__global__ void conv_naive(const float* __restrict__ x, const float* __restrict__ w,
                           const float* __restrict__ bias, float* __restrict__ out) {
    int idx = blockIdx.x * 256 + threadIdx.x;
    if (idx >= NB * KOC * HW * HW) return;
    int ow = idx % 56, t = idx / 56, oh = t % 56, t2 = t / 56, ko = t2 % 256, n = t2 / 256;
    float accv = bias[ko];
    for (int c = 0; c < CI; ++c)
        for (int r = 0; r < 3; ++r) {
            int ih = oh - 1 + r;
            if (ih < 0 || ih >= HW) continue;
            for (int s = 0; s < 3; ++s) {
                int iw = ow - 1 + s;
                if (iw < 0 || iw >= HW) continue;
                accv += x[((size_t)(n * CI + c) * HW + ih) * HW + iw] *
                        w[((size_t)(ko * CI + c) * 3 + r) * 3 + s];
            }
        }
    out[idx] = accv;
}

extern "C" void kernel_launch(void* const* d_in, const int* in_sizes, int n_in,
                              void* d_out, int out_size, void* d_ws, size_t ws_size,
                              hipStream_t stream) {
    const float* x    = (const float*)d_in[0];
    const float* w    = (const float*)d_in[1];
    const float* bias = (const float*)d_in[2];
    float* out = (float*)d_out;

    size_t need = XP_OFF_BYTES + (size_t)XP_ELEMS * 2;
    if (ws_size < need) {
        int tot = NB * KOC * HW * HW;
        conv_naive<<<dim3((tot + 255) / 256), dim3(256), 0, stream>>>(x, w, bias, out);
        return;
    }

    unsigned short* wbp = (unsigned short*)d_ws;
    unsigned short* xpd = (unsigned short*)((char*)d_ws + XP_OFF_BYTES);

    hipMemsetAsync(xpd, 0, (size_t)XP_ELEMS * 2, stream);   // zero padding border
    wt_bf16<<<dim3((KOC * CI + 255) / 256), dim3(256), 0, stream>>>(w, wbp);
    pad_nhwc_bf16<<<dim3(NB * HW), dim3(256), 0, stream>>>(x, xpd);

    dim3 grid(MTOT / 128, 2);
    conv_mfma<<<grid, dim3(256), 0, stream>>>(xpd, wbp, bias, out);
}

// Round 2
// 115.387 us; speedup vs baseline: 1.0725x; 1.0725x over previous
//
#include <hip/hip_runtime.h>

typedef int   v4i __attribute__((ext_vector_type(4)));
typedef float v4f __attribute__((ext_vector_type(4)));
typedef unsigned short ushort_t;

#define NB 32
#define CI 128
#define HW 56
#define KOC 256
#define HP 58
#define MTOT (NB*HW*HW)          // 100352
#define XP_ELEMS ((size_t)NB*HP*HP*CI)   // 13778944
#define XP_OFF_BYTES ((size_t)1<<20)

__device__ __forceinline__ unsigned short f2bf(float f) {
    unsigned int u = __builtin_bit_cast(unsigned int, f);
    u += 0x7fffu + ((u >> 16) & 1u);   // round-to-nearest-even
    return (unsigned short)(u >> 16);
}

__device__ __forceinline__ void gload16(const void* g, void* l) {
    __builtin_amdgcn_global_load_lds(
        (const __attribute__((address_space(1))) void*)g,
        (__attribute__((address_space(3))) void*)l, 16, 0, 0);
}

// ---- weight (256,128,3,3) f32 -> Wb[rs][ko][c] bf16 (c contiguous)
__global__ void wt_bf16(const float* __restrict__ w, ushort_t* __restrict__ wb) {
    int t = blockIdx.x * 256 + threadIdx.x;      // t = ko*128 + c
    if (t >= KOC * CI) return;
    const float* src = w + (size_t)t * 9;
    int ko = t >> 7, c = t & 127;
    #pragma unroll
    for (int rs = 0; rs < 9; ++rs)
        wb[(size_t)(rs * KOC + ko) * CI + c] = f2bf(src[rs]);
}

// ---- x NCHW f32 -> padded NHWC bf16 Xp[n][58][58][128] (interior only)
__global__ void pad_nhwc_bf16(const float* __restrict__ x, ushort_t* __restrict__ xp) {
    __shared__ ushort_t tile[HW][136];
    int b = blockIdx.x;                          // n*56 + h
    int n = b / HW, h = b % HW;
    int tid = threadIdx.x;
    const float* xr = x + (size_t)n * CI * HW * HW + (size_t)h * HW;
    for (int idx = tid; idx < CI * HW; idx += 256) {
        int c = idx / HW, w = idx % HW;
        tile[w][c] = f2bf(xr[(size_t)c * (HW * HW) + w]);
    }
    __syncthreads();
    ushort_t* xpr = xp + ((size_t)(n * HP + (h + 1)) * HP + 1) * CI;
    for (int idx = tid; idx < (HW * CI) / 8; idx += 256) {
        int w = idx >> 4, c8 = (idx & 15) * 8;
        *reinterpret_cast<uint4*>(xpr + (size_t)w * CI + c8) =
            *reinterpret_cast<const uint4*>(&tile[w][c8]);
    }
}

// ---- zero only the padding border of Xp (replaces 27.6 MB memset with 1.9 MB)
__global__ void border_zero(ushort_t* __restrict__ xp) {
    int t = blockIdx.x * 256 + threadIdx.x;      // 32 * 228 * 16 stores of 16B
    if (t >= NB * 228 * 16) return;
    int c16 = t & 15;
    int p = (t >> 4) % 228;
    int n = t / (228 * 16);
    int h, wc;
    if (p < 58)       { h = 0;               wc = p; }
    else if (p < 116) { h = 57;              wc = p - 58; }
    else { int q = p - 116; h = 1 + (q >> 1); wc = (q & 1) * 57; }
    size_t off = ((size_t)(n * HP + h) * HP + wc) * CI + (size_t)c16 * 8;
    uint4 z; z.x = z.y = z.z = z.w = 0u;
    *reinterpret_cast<uint4*>(xp + off) = z;
}

// ---- main: implicit-GEMM conv, m97 structure: global_load_lds + dbuf BK=64
__global__ __launch_bounds__(256, 2) void conv_mfma(
    const ushort_t* __restrict__ xp,
    const ushort_t* __restrict__ wb,
    const float* __restrict__ bias,
    float* __restrict__ out)
{
    __shared__ alignas(16) ushort_t sW[2][128 * 64];   // [buf][row(ko)][64c], 128B rows
    __shared__ alignas(16) ushort_t sX[2][128 * 64];   // [buf][row(m)][64c]

    const int tid  = threadIdx.x;
    const int lane = tid & 63;
    const int wv   = tid >> 6;                   // wave 0..3
    const int wko  = wv >> 1, wm = wv & 1;       // 2x2 wave grid, 64x64 each
    const int m0   = blockIdx.x * 128;
    const int ko0  = blockIdx.y * 128;

    // ---- staging sources: wave wv, sub-call j covers rows wv*32+j*8 .. +8
    // LDS dest is linear (base+lane*16): lane -> row=base+(lane>>3), slot=(lane&7).
    // LDS slot(row,s) must hold global chunk c16 = s ^ (row&7)  (read-side swizzle),
    // so source chunk for lane = (lane&7) ^ (lane>>3).
    const int srow   = lane >> 3;                // 0..7
    const int schunk = (lane & 7) ^ srow;        // inverse-swizzled source 16B chunk
    const ushort_t* wsrc[4];
    const ushort_t* xsrc[4];
    #pragma unroll
    for (int j = 0; j < 4; ++j) {
        int row = wv * 32 + j * 8 + srow;
        wsrc[j] = wb + (size_t)(ko0 + row) * CI + schunk * 8;
        int m = m0 + row;
        int n = m / 3136, tt = m % 3136, oh = tt / 56, ow = tt % 56;
        xsrc[j] = xp + ((size_t)(n * HP + oh) * HP + ow) * CI + schunk * 8;
    }

    // ---- fragment read offsets (elems): row*64 + (((h*4+kc) ^ (row&7))*8)
    const int lm = lane & 15, lk = lane >> 4, l7 = lane & 7;
    int offA[4][2], offB[4][2];
    #pragma unroll
    for (int a = 0; a < 4; ++a)
        #pragma unroll
        for (int h = 0; h < 2; ++h) {
            int rowA = wko * 64 + a * 16 + lm;
            int rowB = wm  * 64 + a * 16 + lm;
            int s = (h * 4 + lk) ^ l7;
            offA[a][h] = rowA * 64 + s * 8;
            offB[a][h] = rowB * 64 + s * 8;
        }

    v4f acc[4][4];
    const v4f vzero = {0.f, 0.f, 0.f, 0.f};
    #pragma unroll
    for (int a = 0; a < 4; ++a)
        #pragma unroll
        for (int b = 0; b < 4; ++b) acc[a][b] = vzero;

    auto stage = [&](int buf, int t) {
        int rs = t >> 1;
        int r  = (rs * 11) >> 5;                 // rs/3 for rs<9
        int s  = rs - r * 3;
        int ch = (t & 1) << 6;                   // 0 or 64 elems
        int woff = rs * (KOC * CI) + ch;
        int xoff = (r * HP + s) * CI + ch;
        char* dW = (char*)&sW[0][0] + buf * 16384 + wv * 4096;
        char* dX = (char*)&sX[0][0] + buf * 16384 + wv * 4096;
        #pragma unroll
        for (int j = 0; j < 4; ++j) {
            gload16(wsrc[j] + woff, dW + j * 1024);
            gload16(xsrc[j] + xoff, dX + j * 1024);
        }
    };

    stage(0, 0);
    __syncthreads();                              // drains vmcnt(0) + barrier

    for (int t = 0; t < 18; ++t) {
        int cur = t & 1;
        if (t < 17) stage(cur ^ 1, t + 1);        // next-tile loads in flight under MFMA

        const ushort_t* bW = &sW[cur][0];
        const ushort_t* bX = &sX[cur][0];
        #pragma unroll
        for (int h = 0; h < 2; ++h) {
            v4i af[4], bf[4];
            #pragma unroll
            for (int a = 0; a < 4; ++a)
                af[a] = *reinterpret_cast<const v4i*>(bW + offA[a][h]);
            #pragma unroll
            for (int b = 0; b < 4; ++b)
                bf[b] = *reinterpret_cast<const v4i*>(bX + offB[b][h]);
            __builtin_amdgcn_s_setprio(1);
            #pragma unroll
            for (int a = 0; a < 4; ++a)
                #pragma unroll
                for (int b = 0; b < 4; ++b)
                    asm volatile("v_mfma_f32_16x16x32_bf16 %0, %1, %2, %0"
                                 : "+v"(acc[a][b]) : "v"(af[a]), "v"(bf[b]));
            __builtin_amdgcn_s_setprio(0);
        }
        __syncthreads();                          // one barrier + vmcnt drain per iter
    }

    // MFMA->VALU hazard fence
    asm volatile("s_nop 7\n\ts_nop 7\n\ts_nop 7"
        : "+v"(acc[0][0]), "+v"(acc[0][1]), "+v"(acc[0][2]), "+v"(acc[0][3]),
          "+v"(acc[1][0]), "+v"(acc[1][1]), "+v"(acc[1][2]), "+v"(acc[1][3]),
          "+v"(acc[2][0]), "+v"(acc[2][1]), "+v"(acc[2][2]), "+v"(acc[2][3]),
          "+v"(acc[3][0]), "+v"(acc[3][1]), "+v"(acc[3][2]), "+v"(acc[3][3]));

    // epilogue: D row=(lane>>4)*4+reg -> ko ; col=lane&15 -> m (coalesced stores)
    const int koBase = ko0 + wko * 64 + (lane >> 4) * 4;
    float bv[4][4];
    #pragma unroll
    for (int a = 0; a < 4; ++a)
        #pragma unroll
        for (int r = 0; r < 4; ++r)
            bv[a][r] = bias[koBase + a * 16 + r];

    #pragma unroll
    for (int b = 0; b < 4; ++b) {
        int mcol = m0 + wm * 64 + b * 16 + (lane & 15);
        int n = mcol / 3136, t4 = mcol % 3136, oh = t4 / 56, ow = t4 % 56;
        size_t obase = (size_t)n * (KOC * 3136) + (size_t)oh * 56 + ow;
        #pragma unroll
        for (int a = 0; a < 4; ++a) {
            int kk = koBase + a * 16;
            #pragma unroll
            for (int r = 0; r < 4; ++r)
                out[obase + (size_t)(kk + r) * 3136] = acc[a][b][r] + bv[a][r];
        }
    }
}

// ---- insurance path if workspace is too small
__global__ void conv_naive(const float* __restrict__ x, const float* __restrict__ w,
                           const float* __restrict__ bias, float* __restrict__ out) {
    int idx = blockIdx.x * 256 + threadIdx.x;
    if (idx >= NB * KOC * HW * HW) return;
    int ow = idx % 56, t = idx / 56, oh = t % 56, t2 = t / 56, ko = t2 % 256, n = t2 / 256;
    float accv = bias[ko];
    for (int c = 0; c < CI; ++c)
        for (int r = 0; r < 3; ++r) {
            int ih = oh - 1 + r;
            if (ih < 0 || ih >= HW) continue;
            for (int s = 0; s < 3; ++s) {
                int iw = ow - 1 + s;
                if (iw < 0 || iw >= HW) continue;
                accv += x[((size_t)(n * CI + c) * HW + ih) * HW + iw] *
                        w[((size_t)(ko * CI + c) * 3 + r) * 3 + s];
            }
        }
    out[idx] = accv;
}

extern "C" void kernel_launch(void* const* d_in, const int* in_sizes, int n_in,
                              void* d_out, int out_size, void* d_ws, size_t ws_size,
                              hipStream_t stream) {
    const float* x    = (const float*)d_in[0];
    const float* w    = (const float*)d_in[1];
    const float* bias = (const float*)d_in[2];
    float* out = (float*)d_out;

    size_t need = XP_OFF_BYTES + XP_ELEMS * 2;
    if (ws_size < need) {
        int tot = NB * KOC * HW * HW;
        conv_naive<<<dim3((tot + 255) / 256), dim3(256), 0, stream>>>(x, w, bias, out);
        return;
    }

    ushort_t* wbp = (ushort_t*)d_ws;
    ushort_t* xpd = (ushort_t*)((char*)d_ws + XP_OFF_BYTES);

    border_zero<<<dim3((NB * 228 * 16 + 255) / 256), dim3(256), 0, stream>>>(xpd);
    wt_bf16<<<dim3((KOC * CI + 255) / 256), dim3(256), 0, stream>>>(w, wbp);
    pad_nhwc_bf16<<<dim3(NB * HW), dim3(256), 0, stream>>>(x, xpd);

    dim3 grid(MTOT / 128, 2);
    conv_mfma<<<grid, dim3(256), 0, stream>>>(xpd, wbp, bias, out);
}

// Round 3
// 104.190 us; speedup vs baseline: 1.1878x; 1.1075x over previous
//
#include <hip/hip_runtime.h>

typedef int   v4i __attribute__((ext_vector_type(4)));
typedef float v4f __attribute__((ext_vector_type(4)));
typedef unsigned short ushort_t;

#define NB 32
#define CI 128
#define HW 56
#define KOC 256
#define HP 58
#define MTOT (NB*HW*HW)                  // 100352
#define XP_ELEMS ((size_t)NB*HP*HP*CI)   // 13778944
#define XP_OFF_BYTES ((size_t)1<<20)

__device__ __forceinline__ unsigned short f2bf(float f) {
    unsigned int u = __builtin_bit_cast(unsigned int, f);
    u += 0x7fffu + ((u >> 16) & 1u);   // round-to-nearest-even
    return (unsigned short)(u >> 16);
}

__device__ __forceinline__ void gload16(const void* g, void* l) {
    __builtin_amdgcn_global_load_lds(
        (const __attribute__((address_space(1))) void*)g,
        (__attribute__((address_space(3))) void*)l, 16, 0, 0);
}

// ---- weight (256,128,3,3) f32 -> Wb[rs][ko][c] bf16 (c contiguous)
__global__ void wt_bf16(const float* __restrict__ w, ushort_t* __restrict__ wb) {
    int t = blockIdx.x * 256 + threadIdx.x;      // t = ko*128 + c
    if (t >= KOC * CI) return;
    const float* src = w + (size_t)t * 9;
    int ko = t >> 7, c = t & 127;
    #pragma unroll
    for (int rs = 0; rs < 9; ++rs)
        wb[(size_t)(rs * KOC + ko) * CI + c] = f2bf(src[rs]);
}

// ---- x NCHW f32 -> padded NHWC bf16 Xp[n][58][58][128] (interior only)
__global__ void pad_nhwc_bf16(const float* __restrict__ x, ushort_t* __restrict__ xp) {
    __shared__ ushort_t tile[HW][136];
    int b = blockIdx.x;                          // n*56 + h
    int n = b / HW, h = b % HW;
    int tid = threadIdx.x;
    const float* xr = x + (size_t)n * CI * HW * HW + (size_t)h * HW;
    for (int idx = tid; idx < CI * HW; idx += 256) {
        int c = idx / HW, w = idx % HW;
        tile[w][c] = f2bf(xr[(size_t)c * (HW * HW) + w]);
    }
    __syncthreads();
    ushort_t* xpr = xp + ((size_t)(n * HP + (h + 1)) * HP + 1) * CI;
    for (int idx = tid; idx < (HW * CI) / 8; idx += 256) {
        int w = idx >> 4, c8 = (idx & 15) * 8;
        *reinterpret_cast<uint4*>(xpr + (size_t)w * CI + c8) =
            *reinterpret_cast<const uint4*>(&tile[w][c8]);
    }
}

// ---- zero only the padding border of Xp
__global__ void border_zero(ushort_t* __restrict__ xp) {
    int t = blockIdx.x * 256 + threadIdx.x;
    if (t >= NB * 228 * 16) return;
    int c16 = t & 15;
    int p = (t >> 4) % 228;
    int n = t / (228 * 16);
    int h, wc;
    if (p < 58)       { h = 0;               wc = p; }
    else if (p < 116) { h = 57;              wc = p - 58; }
    else { int q = p - 116; h = 1 + (q >> 1); wc = (q & 1) * 57; }
    size_t off = ((size_t)(n * HP + h) * HP + wc) * CI + (size_t)c16 * 8;
    uint4 z; z.x = z.y = z.z = z.w = 0u;
    *reinterpret_cast<uint4*>(xp + off) = z;
}

// ================= main conv: 256x256 tile, 8-phase counted-vmcnt =================
// A = W (ko rows), B = X (m rows). 8 waves: 2(ko-half 128) x 4(m-quarter 64).
// LDS per buf: A planes [kh][256][32e] @16KB, B planes same. 2 bufs = 128 KB.
// Quarter = one 16KB plane = 2 gload16/thread. Swizzle: slot = chunk ^ ((row>>1)&3).

#define BAR() asm volatile("s_barrier" ::: "memory")
#define VMW(n) asm volatile("s_waitcnt vmcnt(" #n ")" ::: "memory")

#define PHASE(BUF, KH, MH, STAGE_STMT, VMSTMT) do {                               \
    const char* pbase = lds + (BUF) * 65536 + (KH) * 16384;                       \
    if ((MH) == 0) {                                                              \
        _Pragma("unroll")                                                         \
        for (int a = 0; a < 8; ++a)                                               \
            af[a] = *reinterpret_cast<const v4i*>(pbase + aoff[a]);               \
    }                                                                             \
    v4i bf0 = *reinterpret_cast<const v4i*>(pbase + boff[(MH)*2]);                \
    v4i bf1 = *reinterpret_cast<const v4i*>(pbase + boff[(MH)*2+1]);              \
    STAGE_STMT;                                                                   \
    VMSTMT;                                                                       \
    BAR();                                                                        \
    __builtin_amdgcn_s_setprio(1);                                                \
    _Pragma("unroll")                                                             \
    for (int a = 0; a < 8; ++a) {                                                 \
        asm volatile("v_mfma_f32_16x16x32_bf16 %0, %1, %2, %0"                    \
                     : "+v"(acc[a][(MH)*2])   : "v"(af[a]), "v"(bf0));            \
        asm volatile("v_mfma_f32_16x16x32_bf16 %0, %1, %2, %0"                    \
                     : "+v"(acc[a][(MH)*2+1]) : "v"(af[a]), "v"(bf1));            \
    }                                                                             \
    __builtin_amdgcn_s_setprio(0);                                                \
    BAR();                                                                        \
} while (0)

__global__ __launch_bounds__(512, 2) void conv_mfma(
    const ushort_t* __restrict__ xp,
    const ushort_t* __restrict__ wb,
    const float* __restrict__ bias,
    float* __restrict__ out)
{
    __shared__ alignas(16) char lds[131072];

    const int tid  = threadIdx.x;
    const int lane = tid & 63;
    const int wv   = tid >> 6;          // 0..7
    const int wko2 = wv >> 2;           // ko half (128 rows)
    const int wm4  = wv & 3;            // m quarter (64 rows)
    const int m0   = blockIdx.x * 256;
    const int lm = lane & 15, lk = lane >> 4;

    // ---- staging sources (per thread): rows srow, srow+128; chunk swizzled
    const int srow = tid >> 2;                        // 0..127
    const int sc   = (tid & 3) ^ ((tid >> 3) & 3);    // chunk, same for both j
    const size_t wA0 = (size_t)srow * CI + sc * 8;
    const size_t wA1 = (size_t)(srow + 128) * CI + sc * 8;
    size_t xB0, xB1;
    {
        int mm = m0 + srow;
        int n = mm / 3136, tt = mm % 3136, oh = tt / 56, ow = tt % 56;
        xB0 = ((size_t)(n * HP + oh) * HP + ow) * CI + sc * 8;
        mm = m0 + 128 + srow;
        n = mm / 3136; tt = mm % 3136; oh = tt / 56; ow = tt % 56;
        xB1 = ((size_t)(n * HP + oh) * HP + ow) * CI + sc * 8;
    }

    auto stageA = [&](int buf, int kh, int kt) {
        int rs = kt >> 1, ch = (kt & 1) << 6;
        size_t g = (size_t)rs * (KOC * CI) + ch + kh * 32;
        char* d = lds + buf * 65536 + kh * 16384 + wv * 1024;
        gload16(wb + wA0 + g, d);
        gload16(wb + wA1 + g, d + 8192);
    };
    auto stageB = [&](int buf, int kh, int kt) {
        int rs = kt >> 1, ch = (kt & 1) << 6;
        int r = (rs * 11) >> 5, s = rs - r * 3;
        size_t g = (size_t)(r * HP + s) * CI + ch + kh * 32;
        char* d = lds + buf * 65536 + 32768 + kh * 16384 + wv * 1024;
        gload16(xp + xB0 + g, d);
        gload16(xp + xB1 + g, d + 8192);
    };

    // ---- fragment LDS byte offsets (within a plane)
    int aoff[8], boff[4];
    #pragma unroll
    for (int a = 0; a < 8; ++a) {
        int row = wko2 * 128 + a * 16 + lm;
        aoff[a] = row * 64 + ((lk ^ ((row >> 1) & 3)) * 16);
    }
    #pragma unroll
    for (int bb = 0; bb < 4; ++bb) {
        int row = wm4 * 64 + bb * 16 + lm;
        boff[bb] = 32768 + row * 64 + ((lk ^ ((row >> 1) & 3)) * 16);
    }

    v4f acc[8][4];
    const v4f vzero = {0.f, 0.f, 0.f, 0.f};
    #pragma unroll
    for (int a = 0; a < 8; ++a)
        #pragma unroll
        for (int b = 0; b < 4; ++b) acc[a][b] = vzero;

    v4i af[8];

    // ---- prologue: tile0 all 4 quarters + tile1 k0 quarters (6 events, 12 loads)
    stageA(0, 0, 0); stageB(0, 0, 0); stageA(0, 1, 0); stageB(0, 1, 0);
    stageA(1, 0, 1); stageB(1, 0, 1);
    VMW(8);          // retire tile0 A[k0], B[k0]
    BAR();

    // ---- main loop: iter t computes tiles 2t (buf0), 2t+1 (buf1)
    for (int t = 0; t < 8; ++t) {
        int e2 = 2 * t;
        PHASE(0, 0, 0, stageA(1, 1, e2 + 1), VMW(8));
        PHASE(0, 0, 1, stageB(1, 1, e2 + 1), VMW(8));
        PHASE(0, 1, 0, stageA(0, 0, e2 + 2), VMW(8));
        PHASE(0, 1, 1, stageB(0, 0, e2 + 2), VMW(8));
        PHASE(1, 0, 0, stageA(0, 1, e2 + 2), VMW(8));
        PHASE(1, 0, 1, stageB(0, 1, e2 + 2), VMW(8));
        PHASE(1, 1, 0, stageA(1, 0, e2 + 3), VMW(8));
        PHASE(1, 1, 1, stageB(1, 0, e2 + 3), VMW(8));
    }

    // ---- peeled final iter: tiles 16 (buf0), 17 (buf1); drain with counted waits
    PHASE(0, 0, 0, stageA(1, 1, 17), VMW(8));
    PHASE(0, 0, 1, stageB(1, 1, 17), VMW(8));
    PHASE(0, 1, 0, (void)0, VMW(8));
    PHASE(0, 1, 1, (void)0, VMW(4));
    PHASE(1, 0, 0, (void)0, VMW(4));
    PHASE(1, 0, 1, (void)0, VMW(0));
    PHASE(1, 1, 0, (void)0, VMW(0));
    PHASE(1, 1, 1, (void)0, VMW(0));

    // ---- MFMA->VALU hazard fence (asm MFMAs: compiler doesn't add hazard nops)
    asm volatile("s_nop 7\n\ts_nop 7"
        : "+v"(acc[0][0]), "+v"(acc[0][1]), "+v"(acc[0][2]), "+v"(acc[0][3]),
          "+v"(acc[1][0]), "+v"(acc[1][1]), "+v"(acc[1][2]), "+v"(acc[1][3]),
          "+v"(acc[2][0]), "+v"(acc[2][1]), "+v"(acc[2][2]), "+v"(acc[2][3]),
          "+v"(acc[3][0]), "+v"(acc[3][1]), "+v"(acc[3][2]), "+v"(acc[3][3]));
    asm volatile("s_nop 7\n\ts_nop 7"
        : "+v"(acc[4][0]), "+v"(acc[4][1]), "+v"(acc[4][2]), "+v"(acc[4][3]),
          "+v"(acc[5][0]), "+v"(acc[5][1]), "+v"(acc[5][2]), "+v"(acc[5][3]),
          "+v"(acc[6][0]), "+v"(acc[6][1]), "+v"(acc[6][2]), "+v"(acc[6][3]),
          "+v"(acc[7][0]), "+v"(acc[7][1]), "+v"(acc[7][2]), "+v"(acc[7][3]));

    // ---- epilogue: D row=(lane>>4)*4+r -> ko ; col=lane&15 -> m (64B-contig stores)
    const int koB = wko2 * 128 + lk * 4;
    v4f bv[8];
    #pragma unroll
    for (int a = 0; a < 8; ++a)
        bv[a] = *reinterpret_cast<const v4f*>(bias + koB + a * 16);

    #pragma unroll
    for (int bb = 0; bb < 4; ++bb) {
        int mcol = m0 + wm4 * 64 + bb * 16 + lm;
        int n = mcol / 3136, t4 = mcol % 3136, oh = t4 / 56, ow = t4 % 56;
        size_t obase = (size_t)n * (KOC * 3136) + (size_t)oh * 56 + ow;
        #pragma unroll
        for (int a = 0; a < 8; ++a) {
            int kk = koB + a * 16;
            #pragma unroll
            for (int r = 0; r < 4; ++r)
                out[obase + (size_t)(kk + r) * 3136] = acc[a][bb][r] + bv[a][r];
        }
    }
}

// ---- insurance path if workspace is too small
__global__ void conv_naive(const float* __restrict__ x, const float* __restrict__ w,
                           const float* __restrict__ bias, float* __restrict__ out) {
    int idx = blockIdx.x * 256 + threadIdx.x;
    if (idx >= NB * KOC * HW * HW) return;
    int ow = idx % 56, t = idx / 56, oh = t % 56, t2 = t / 56, ko = t2 % 256, n = t2 / 256;
    float accv = bias[ko];
    for (int c = 0; c < CI; ++c)
        for (int r = 0; r < 3; ++r) {
            int ih = oh - 1 + r;
            if (ih < 0 || ih >= HW) continue;
            for (int s = 0; s < 3; ++s) {
                int iw = ow - 1 + s;
                if (iw < 0 || iw >= HW) continue;
                accv += x[((size_t)(n * CI + c) * HW + ih) * HW + iw] *
                        w[((size_t)(ko * CI + c) * 3 + r) * 3 + s];
            }
        }
    out[idx] = accv;
}

extern "C" void kernel_launch(void* const* d_in, const int* in_sizes, int n_in,
                              void* d_out, int out_size, void* d_ws, size_t ws_size,
                              hipStream_t stream) {
    const float* x    = (const float*)d_in[0];
    const float* w    = (const float*)d_in[1];
    const float* bias = (const float*)d_in[2];
    float* out = (float*)d_out;

    size_t need = XP_OFF_BYTES + XP_ELEMS * 2;
    if (ws_size < need) {
        int tot = NB * KOC * HW * HW;
        conv_naive<<<dim3((tot + 255) / 256), dim3(256), 0, stream>>>(x, w, bias, out);
        return;
    }

    ushort_t* wbp = (ushort_t*)d_ws;
    ushort_t* xpd = (ushort_t*)((char*)d_ws + XP_OFF_BYTES);

    border_zero<<<dim3((NB * 228 * 16 + 255) / 256), dim3(256), 0, stream>>>(xpd);
    wt_bf16<<<dim3((KOC * CI + 255) / 256), dim3(256), 0, stream>>>(w, wbp);
    pad_nhwc_bf16<<<dim3(NB * HW), dim3(256), 0, stream>>>(x, xpd);

    conv_mfma<<<dim3(MTOT / 256), dim3(512), 0, stream>>>(xpd, wbp, bias, out);
}